// Round 15
// baseline (387.027 us; speedup 1.0000x reference)
//
#include <hip/hip_runtime.h>
#include <hip/hip_bf16.h>

#define NPTS 4096
#define CIN 64
#define COUT 128
#define BATCH 8
#define KNN 8
#define NCH 12              // candidates per column-half
#define NCT 24              // total candidates per row
#define TOTROWS (BATCH * NPTS)   // 32768

using short8 = __attribute__((ext_vector_type(8))) short;
using f32x4  = __attribute__((ext_vector_type(4))) float;

__device__ __forceinline__ unsigned short f2bf_rne(float f) {
    unsigned int u = __float_as_uint(f);
    unsigned int r = (u + 0x7fffu + ((u >> 16) & 1u)) >> 16;
    return (unsigned short)r;
}

// single-instruction median-of-3 (VOP3, gfx9+). Emit directly; backend matching
// from C min/max is not guaranteed.
__device__ __forceinline__ unsigned int umed3(unsigned int a, unsigned int b, unsigned int c) {
    unsigned int d;
    asm("v_med3_u32 %0, %1, %2, %3" : "=v"(d) : "v"(a), "v"(b), "v"(c));
    return d;
}

// ---------------- Kernel 1: pack x -> bf16(RNE) rows (128B) + norms (xxn = 1000-xx fp32, xxd fp64) ----------------
__global__ __launch_bounds__(256) void prep_kernel(const float* __restrict__ x,
                                                   unsigned short* __restrict__ xpack,
                                                   float* __restrict__ xxn,
                                                   double* __restrict__ xxd) {
    int i   = blockIdx.x * 256 + threadIdx.x;    // 0 .. 262143
    int row = i >> 3, g = i & 7;                 // 8 threads per row
    const float* src = x + (size_t)row * CIN + g * 8;
    float4 v0 = *(const float4*)src;
    float4 v1 = *(const float4*)(src + 4);
    float f[8] = {v0.x, v0.y, v0.z, v0.w, v1.x, v1.y, v1.z, v1.w};

    unsigned int h[8];
    double s = 0.0;
    #pragma unroll
    for (int j = 0; j < 8; ++j) {
        h[j] = (unsigned int)f2bf_rne(f[j]);
        s += (double)f[j] * (double)f[j];
    }
    uint4 hi;
    hi.x = h[0] | (h[1] << 16); hi.y = h[2] | (h[3] << 16);
    hi.z = h[4] | (h[5] << 16); hi.w = h[6] | (h[7] << 16);
    *(uint4*)&xpack[(size_t)row * 64 + g * 8] = hi;

    s += __shfl_xor(s, 1);
    s += __shfl_xor(s, 2);
    s += __shfl_xor(s, 4);
    if (g == 0) { xxn[row] = 1000.f - (float)s; xxd[row] = s; }
}

// ---------------- Kernel 2: bf16 MFMA scores — 32-row blocks, parity-split waves, 6 blocks/CU (24 waves) ----------------
// key = bits(float(score+1000)) with low 7 mantissa bits = chunk position p (0..127).
// col = half*2048 + p*16 + lrow. Per-lane 8-deep sorted u32 lists -> two-pass-by-parity block merge
// -> top-12/half (NCH/NCT unchanged -> rerank untouched). bf16 err + 0.008 trunc << rank8->12 margin.
//
// Measured history:
//  R10: 64-row blocks @ bounds(256,6): VGPR 40, NO spill, knn 97us — but grid 1024 = 4 blocks/CU cap.
//  R14: this parity-split structure @ bounds(256,8): allocator split 64-reg budget ~32arch+32acc ->
//       VGPR 32, spill (FETCH 26->103MB). 8 waves/SIMD is infeasible for ~40-reg need. Math verified OK.
//       Also: merge rotation pos=(tid*4+c)&127 -> bank (tid*4+c)%32 -> 8-way conflict (2.1M cycles).
//  => bounds(256,6): budget 85 >= 40 need (R10-verified operating point); grid 2048 -> 6 blocks/CU
//     resident = 24 waves/CU (1.5x R10). Merge rotation (tid+c)&127: bank (tid*129+c)%32 distinct.
__global__ __launch_bounds__(256, 6) void knn_cand_kernel(const unsigned short* __restrict__ xpack,
                                                          const float* __restrict__ xxn,
                                                          int* __restrict__ cand) {
    __shared__ __align__(16) unsigned int mK[4096];          // 16 KB: dbuf overlay / merge scratch
    __shared__ float xxs[128];                               // 2 x 64 norms (double-buffered)
    unsigned short* BUF0 = (unsigned short*)mK;              // 64 rows x 64 ushorts (8 KB, swizzled)
    unsigned short* BUF1 = BUF0 + 4096;                      // second buffer (8 KB)

    const int tid  = threadIdx.x;
    const int n0   = blockIdx.x * 32;
    const int half = blockIdx.y;
    const int b    = blockIdx.z;
    const int wave = tid >> 6;
    const int lane = tid & 63;
    const int lrow = lane & 15;
    const int quad = lane >> 4;
    const int rg   = wave & 1;                               // row group: 16 query rows
    const int cs   = wave >> 1;                              // chunk parity within the half
    const int colbase = half << 11;                          // first candidate row of this half

    const unsigned short* xp = xpack + ((size_t)b << 12) * 64;
    const float* xnn = xxn + (b << 12);

    // A fragments: direct global load (L2-resident, coalesced); parity wave-pairs duplicate (L1-hit)
    const int arow = n0 + rg * 16 + lrow;
    short8 ah0 = *(const short8*)&xp[arow * 64 + quad * 8];
    short8 ah1 = *(const short8*)&xp[arow * 64 + 32 + quad * 8];

    unsigned int keys[4][8];
    #pragma unroll
    for (int r = 0; r < 4; ++r)
        #pragma unroll
        for (int j = 0; j < 8; ++j) keys[r][j] = 0u;

    uint4 pr[2]; float pxv;
    // staging geometry: 2 chunks/thread (64 rows x 8 chunks = 512 = 256 thr x 2);
    // chunk G -> row G>>3, slot (G&7)^(row&7) (XOR swizzle, verified conflict-free R7/R10)
    int swi[2];
    #pragma unroll
    for (int k = 0; k < 2; ++k) {
        int G = k * 256 + tid, row = G >> 3, h = G & 7;
        swi[k] = row * 64 + ((h ^ (row & 7)) << 3);          // swizzled ushort index
    }

    // priming: tile 0 -> BUF0 + xxs[0]
    {
        const size_t base0 = (size_t)colbase * 64;
        #pragma unroll
        for (int k = 0; k < 2; ++k) {
            int G = k * 256 + tid;
            pr[k] = *(const uint4*)&xp[base0 + G * 8];
        }
        pxv = (tid < 64) ? xnn[colbase + tid] : 0.f;
        #pragma unroll
        for (int k = 0; k < 2; ++k)
            *(uint4*)&BUF0[swi[k]] = pr[k];
        if (tid < 64) xxs[tid] = pxv;
    }
    __syncthreads();

    for (int ot = 0; ot < 32; ++ot) {
        unsigned short* cur = (ot & 1) ? BUF1 : BUF0;
        unsigned short* nxt = (ot & 1) ? BUF0 : BUF1;
        const float*    xs  = xxs + (ot & 1) * 64;

        // a) issue loads for tile ot+1 (in flight during compute; no other VMEM in the loop)
        if (ot < 31) {
            const size_t base = (size_t)(colbase + (ot + 1) * 64) * 64;
            #pragma unroll
            for (int k = 0; k < 2; ++k) {
                int G = k * 256 + tid;
                pr[k] = *(const uint4*)&xp[base + G * 8];
            }
            if (tid < 64) pxv = xnn[colbase + (ot + 1) * 64 + tid];
        }

        // b) compute this wave's parity chunks of tile ot (p2 = cs, cs+2) — LDS-only reads
        #pragma unroll
        for (int i = 0; i < 2; ++i) {
            const int p2   = cs + 2 * i;
            const int row0 = p2 * 16 + lrow;
            const int s    = lrow & 7;                       // row0&7 == lrow&7
            short8 bh0 = *(const short8*)&cur[row0 * 64 + ((quad ^ s) << 3)];
            short8 bh1 = *(const short8*)&cur[row0 * 64 + (((4 + quad) ^ s) << 3)];
            const float xm = xs[row0];
            f32x4 acc = {0.f, 0.f, 0.f, 0.f};
            acc = __builtin_amdgcn_mfma_f32_16x16x32_bf16(ah0, bh0, acc, 0, 0, 0);
            acc = __builtin_amdgcn_mfma_f32_16x16x32_bf16(ah1, bh1, acc, 0, 0, 0);
            const unsigned int pp = (unsigned int)(ot * 4 + p2);
            #pragma unroll
            for (int r = 0; r < 4; ++r) {
                float v = fmaf(acc[r], 2.f, xm);             // score + 1000 (>0)
                unsigned int t = (__float_as_uint(v) & 0xFFFFFF80u) | pp;
                // med3 insert: j descending so keys[j-1] is still the OLD value
                #pragma unroll
                for (int j = 7; j >= 1; --j)
                    keys[r][j] = umed3(keys[r][j - 1], keys[r][j], t);
                keys[r][0] = keys[r][0] > t ? keys[r][0] : t;
            }
        }

        // c) write prefetch into nxt (swizzled) BEFORE the barrier (pr not live across barrier)
        if (ot < 31) {
            #pragma unroll
            for (int k = 0; k < 2; ++k)
                *(uint4*)&nxt[swi[k]] = pr[k];
            if (tid < 64) xxs[(1 - (ot & 1)) * 64 + tid] = pxv;
        }
        // d) single barrier per tile
        __syncthreads();
    }

    // Two-pass merge by parity: pass A = cs==0 waves dump all keys (then dead), tid<32 scans its
    // row's 128 keys; pass B = cs==1 waves dump, scan continues into same bk/bc.
    // Row layout: row = rg*16 + quad*4 + r (0..31); per row 16 lrow-lanes x 8 keys = 128.
    // Scan rotation (tid+c)&127: bank = (tid*128 + tid + c)%32 = (tid + c)%32 -> conflict-free
    // (R14's tid*4+c rotation was 8-way: 2.1M conflict cycles).
    const int mrow = rg * 16 + quad * 4;

    unsigned int bk[NCH]; int bc[NCH];
    #pragma unroll
    for (int j = 0; j < NCH; ++j) { bk[j] = 0u; bc[j] = 0; }

    #pragma unroll
    for (int phase = 0; phase < 2; ++phase) {
        if (cs == phase) {
            #pragma unroll
            for (int r = 0; r < 4; ++r) {
                uint4 k0 = make_uint4(keys[r][0], keys[r][1], keys[r][2], keys[r][3]);
                uint4 k1 = make_uint4(keys[r][4], keys[r][5], keys[r][6], keys[r][7]);
                *(uint4*)&mK[(mrow + r) * 128 + lrow * 8]     = k0;
                *(uint4*)&mK[(mrow + r) * 128 + lrow * 8 + 4] = k1;
            }
        }
        __syncthreads();
        if (tid < 32) {
            const unsigned int* rowK = mK + tid * 128;
            for (int c = 0; c < 128; ++c) {
                int pos = (tid + c) & 127;
                unsigned int k = rowK[pos];
                if (k > bk[NCH - 1]) {
                    int lr = pos >> 3;
                    int p  = (int)(k & 0x7Fu);
                    int col = (half << 11) + (p << 4) + lr;
                    bk[NCH - 1] = k; bc[NCH - 1] = col;
                    #pragma unroll
                    for (int j = NCH - 1; j > 0; --j) {
                        if (bk[j] > bk[j - 1]) {
                            unsigned int tk = bk[j]; bk[j] = bk[j - 1]; bk[j - 1] = tk;
                            int tc = bc[j]; bc[j] = bc[j - 1]; bc[j - 1] = tc;
                        }
                    }
                }
            }
        }
        __syncthreads();
    }

    if (tid < 32) {
        int* co = cand + ((size_t)((b << 12) + n0 + tid)) * NCT + half * NCH;
        #pragma unroll
        for (int j = 0; j < NCH; ++j) co[j] = bc[j];
    }
}

// ---------------- Kernel 3: exact fp64 re-rank (parallel ranking) + gather/max -> feat ----------------
__global__ __launch_bounds__(256) void rerank_kernel(const float* __restrict__ x,
                                                     const double* __restrict__ xxd,
                                                     const int* __restrict__ cand,
                                                     float* __restrict__ feat) {
    __shared__ double sc[4][NCT];
    __shared__ int    si[4][NCT];
    __shared__ int    sel[4][KNN];
    const int tid = threadIdx.x, wave = tid >> 6, lane = tid & 63;
    const size_t row = (size_t)blockIdx.x * 4 + wave;     // 0..32767
    const int b = (int)(row >> 12);
    const float* xb = x + (((size_t)b) << 12) * CIN;
    const float* xn = x + row * CIN;

    const int cidx = lane & 31, part = lane >> 5;
    if (cidx < NCT) {
        int m = cand[row * NCT + cidx];
        const float* xm = xb + (size_t)m * CIN;
        const float* xa = xn + part * 32;
        const float* xv = xm + part * 32;
        // 4 independent fp64 accumulators: breaks the 32-deep serial FMA chain
        double a0 = 0.0, a1 = 0.0, a2 = 0.0, a3 = 0.0;
        #pragma unroll
        for (int c4 = 0; c4 < 8; c4 += 4) {
            float4 p0 = *(const float4*)&xa[(c4 + 0) * 4];
            float4 q0 = *(const float4*)&xv[(c4 + 0) * 4];
            float4 p1 = *(const float4*)&xa[(c4 + 1) * 4];
            float4 q1 = *(const float4*)&xv[(c4 + 1) * 4];
            float4 p2 = *(const float4*)&xa[(c4 + 2) * 4];
            float4 q2 = *(const float4*)&xv[(c4 + 2) * 4];
            float4 p3 = *(const float4*)&xa[(c4 + 3) * 4];
            float4 q3 = *(const float4*)&xv[(c4 + 3) * 4];
            a0 = fma((double)p0.x, (double)q0.x, a0); a0 = fma((double)p0.y, (double)q0.y, a0);
            a0 = fma((double)p0.z, (double)q0.z, a0); a0 = fma((double)p0.w, (double)q0.w, a0);
            a1 = fma((double)p1.x, (double)q1.x, a1); a1 = fma((double)p1.y, (double)q1.y, a1);
            a1 = fma((double)p1.z, (double)q1.z, a1); a1 = fma((double)p1.w, (double)q1.w, a1);
            a2 = fma((double)p2.x, (double)q2.x, a2); a2 = fma((double)p2.y, (double)q2.y, a2);
            a2 = fma((double)p2.z, (double)q2.z, a2); a2 = fma((double)p2.w, (double)q2.w, a2);
            a3 = fma((double)p3.x, (double)q3.x, a3); a3 = fma((double)p3.y, (double)q3.y, a3);
            a3 = fma((double)p3.z, (double)q3.z, a3); a3 = fma((double)p3.w, (double)q3.w, a3);
        }
        double d = (a0 + a1) + (a2 + a3);
        d += __shfl_xor(d, 32);
        if (part == 0) {
            sc[wave][cidx] = 2.0 * d - xxd[(((size_t)b) << 12) + m];
            si[wave][cidx] = m;
        }
    }
    __syncthreads();

    // parallel exact ranking: lane i counts candidates strictly ahead of it
    if (lane < NCT) {
        double myv = sc[wave][lane];
        int    mym = si[wave][lane];
        int rank = 0;
        #pragma unroll
        for (int c = 0; c < NCT; ++c) {
            double v = sc[wave][c];
            int    m = si[wave][c];
            rank += (v > myv || (v == myv && m < mym)) ? 1 : 0;
        }
        if (rank < KNN) sel[wave][rank] = mym;
    }
    __syncthreads();

    float mx = -3.0e38f;
    #pragma unroll
    for (int j = 0; j < KNN; ++j)
        mx = fmaxf(mx, xb[(size_t)sel[wave][j] * CIN + lane]);
    feat[row * CIN + lane] = mx;
}

// ---------------- Kernel 4: conv (fp32 VALU) -> y + BN stats ----------------
// Channel-contiguous remap: thread owns channels ch4..ch4+3 (ch4=(tid&31)*4) ->
// W read = 1 ds_read_b128 (was 4 scalar b32 at stride 32), Fs = float4 per 4 c-iters
// (was 8 scalar b32), y store = 1 coalesced float4 (was 4 stride-32 scalar stores).
// Per-channel accumulation order (c ascending) unchanged -> bitwise-identical results.
__global__ __launch_bounds__(256) void conv_stats_kernel(const float* __restrict__ feat,
                                                         const float* __restrict__ W,
                                                         float* __restrict__ y,
                                                         float* __restrict__ st) {
    __shared__ float Wt[64 * 128];   // Wt[c][o]
    __shared__ float Fs[64 * 64];
    __shared__ float bs[128], bs2[128];
    const int tid = threadIdx.x;
    const int n0  = blockIdx.x * 64;

    for (int i = tid; i < 8192; i += 256) {
        int o = i >> 6, c = i & 63;
        Wt[c * 128 + o] = W[i];
    }
    for (int i = tid; i < 1024; i += 256)
        ((float4*)Fs)[i] = ((const float4*)(feat + (size_t)n0 * CIN))[i];
    if (tid < 128) { bs[tid] = 0.f; bs2[tid] = 0.f; }
    __syncthreads();

    const int ch4 = (tid & 31) * 4, rg = tid >> 5;
    float ts[4] = {0.f, 0.f, 0.f, 0.f}, ts2[4] = {0.f, 0.f, 0.f, 0.f};
    #pragma unroll
    for (int p = 0; p < 4; ++p) {
        const int r0 = p * 16 + rg * 2;
        float acc0[4] = {0.f, 0.f, 0.f, 0.f}, acc1[4] = {0.f, 0.f, 0.f, 0.f};
        for (int c4 = 0; c4 < 16; ++c4) {
            float4 f0v = *(const float4*)&Fs[r0 * 64 + c4 * 4];
            float4 f1v = *(const float4*)&Fs[(r0 + 1) * 64 + c4 * 4];
            const float f0a[4] = {f0v.x, f0v.y, f0v.z, f0v.w};
            const float f1a[4] = {f1v.x, f1v.y, f1v.z, f1v.w};
            #pragma unroll
            for (int cc = 0; cc < 4; ++cc) {
                float4 w = *(const float4*)&Wt[(c4 * 4 + cc) * 128 + ch4];
                const float wa[4] = {w.x, w.y, w.z, w.w};
                #pragma unroll
                for (int j = 0; j < 4; ++j) {
                    acc0[j] += f0a[cc] * wa[j];
                    acc1[j] += f1a[cc] * wa[j];
                }
            }
        }
        *(float4*)&y[(size_t)(n0 + r0)     * COUT + ch4] = make_float4(acc0[0], acc0[1], acc0[2], acc0[3]);
        *(float4*)&y[(size_t)(n0 + r0 + 1) * COUT + ch4] = make_float4(acc1[0], acc1[1], acc1[2], acc1[3]);
        #pragma unroll
        for (int j = 0; j < 4; ++j) {
            ts[j]  += acc0[j] + acc1[j];
            ts2[j] += acc0[j] * acc0[j] + acc1[j] * acc1[j];
        }
    }
    #pragma unroll
    for (int j = 0; j < 4; ++j) {
        atomicAdd(&bs [ch4 + j], ts[j]);
        atomicAdd(&bs2[ch4 + j], ts2[j]);
    }
    __syncthreads();
    if (tid < 128) {
        atomicAdd(&st[tid],       bs[tid]);
        atomicAdd(&st[128 + tid], bs2[tid]);
    }
}

// ---------------- Kernel 5: elementwise BN + LeakyReLU -> fp32 out ----------------
__global__ __launch_bounds__(256) void norm_out_kernel(const float* __restrict__ y,
                                                       const float* __restrict__ st,
                                                       const float* __restrict__ gamma,
                                                       const float* __restrict__ beta,
                                                       float* __restrict__ out) {
    size_t i = ((size_t)blockIdx.x * 256 + threadIdx.x) * 4;
    int c0 = (int)(i & 127);
    float4 v = *(const float4*)&y[i];
    float o[4];
    const float inv = 1.0f / (float)TOTROWS;
    #pragma unroll
    for (int j = 0; j < 4; ++j) {
        int c = c0 + j;
        float m  = st[c] * inv;
        float vr = st[128 + c] * inv - m * m;
        float sc = rsqrtf(vr + 1e-5f) * gamma[c];
        float t  = (((const float*)&v)[j] - m) * sc + beta[c];
        o[j] = (t >= 0.f) ? t : 0.01f * t;
    }
    *(float4*)&out[i] = make_float4(o[0], o[1], o[2], o[3]);
}

extern "C" void kernel_launch(void* const* d_in, const int* in_sizes, int n_in,
                              void* d_out, int out_size, void* d_ws, size_t ws_size,
                              hipStream_t stream) {
    (void)in_sizes; (void)n_in; (void)out_size; (void)ws_size;
    const float* x     = (const float*)d_in[0];
    const float* W     = (const float*)d_in[1];
    const float* gamma = (const float*)d_in[2];
    const float* beta  = (const float*)d_in[3];
    // d_in[4] is k == 8 (compile-time KNN)
    float* out = (float*)d_out;

    // workspace (~28.4 MB): xxn 128K | xxd 256K | cand 4M | feat 8M | region 16M (xpack 4M, reused as y) | st
    char*   ws    = (char*)d_ws;
    float*  xxn   = (float*)ws;
    double* xxd   = (double*)(ws + 131072);
    int*    cand  = (int*)(ws + 131072 + 262144);
    float*  feat  = (float*)(ws + 131072 + 262144 + 4194304);
    unsigned short* xpack = (unsigned short*)(ws + 131072 + 262144 + 4194304 + 8388608);
    float*  y     = (float*)xpack;   // xpack (4 MB used) dead after knn_cand; y is 16 MB fp32
    float*  st    = (float*)(ws + 131072 + 262144 + 4194304 + 8388608 + 16777216);

    hipMemsetAsync(st, 0, 256 * sizeof(float), stream);
    prep_kernel      <<<TOTROWS * 8 / 256, 256, 0, stream>>>(x, xpack, xxn, xxd);
    knn_cand_kernel  <<<dim3(NPTS / 32, 2, BATCH), 256, 0, stream>>>(xpack, xxn, cand);
    rerank_kernel    <<<TOTROWS / 4, 256, 0, stream>>>(x, xxd, cand, feat);
    conv_stats_kernel<<<TOTROWS / 64, 256, 0, stream>>>(feat, W, y, st);
    norm_out_kernel  <<<(TOTROWS * COUT) / (256 * 4), 256, 0, stream>>>(y, st, gamma, beta, out);
}

// Round 16
// 244.508 us; speedup vs baseline: 1.5829x; 1.5829x over previous
//
#include <hip/hip_runtime.h>
#include <hip/hip_bf16.h>

#define NPTS 4096
#define CIN 64
#define COUT 128
#define BATCH 8
#define KNN 8
#define NCH 12              // candidates per column-half
#define NCT 24              // total candidates per row
#define TOTROWS (BATCH * NPTS)   // 32768

using short8 = __attribute__((ext_vector_type(8))) short;
using f32x4  = __attribute__((ext_vector_type(4))) float;

__device__ __forceinline__ unsigned short f2bf_rne(float f) {
    unsigned int u = __float_as_uint(f);
    unsigned int r = (u + 0x7fffu + ((u >> 16) & 1u)) >> 16;
    return (unsigned short)r;
}

// single-instruction median-of-3 (VOP3, gfx9+). Emit directly; backend matching
// from C min/max is not guaranteed.
__device__ __forceinline__ unsigned int umed3(unsigned int a, unsigned int b, unsigned int c) {
    unsigned int d;
    asm("v_med3_u32 %0, %1, %2, %3" : "=v"(d) : "v"(a), "v"(b), "v"(c));
    return d;
}

// ---------------- Kernel 1: pack x -> bf16(RNE) rows (128B) + norms (xxn = 1000-xx fp32, xxd fp64) ----------------
__global__ __launch_bounds__(256) void prep_kernel(const float* __restrict__ x,
                                                   unsigned short* __restrict__ xpack,
                                                   float* __restrict__ xxn,
                                                   double* __restrict__ xxd) {
    int i   = blockIdx.x * 256 + threadIdx.x;    // 0 .. 262143
    int row = i >> 3, g = i & 7;                 // 8 threads per row
    const float* src = x + (size_t)row * CIN + g * 8;
    float4 v0 = *(const float4*)src;
    float4 v1 = *(const float4*)(src + 4);
    float f[8] = {v0.x, v0.y, v0.z, v0.w, v1.x, v1.y, v1.z, v1.w};

    unsigned int h[8];
    double s = 0.0;
    #pragma unroll
    for (int j = 0; j < 8; ++j) {
        h[j] = (unsigned int)f2bf_rne(f[j]);
        s += (double)f[j] * (double)f[j];
    }
    uint4 hi;
    hi.x = h[0] | (h[1] << 16); hi.y = h[2] | (h[3] << 16);
    hi.z = h[4] | (h[5] << 16); hi.w = h[6] | (h[7] << 16);
    *(uint4*)&xpack[(size_t)row * 64 + g * 8] = hi;

    s += __shfl_xor(s, 1);
    s += __shfl_xor(s, 2);
    s += __shfl_xor(s, 4);
    if (g == 0) { xxn[row] = 1000.f - (float)s; xxd[row] = s; }
}

// ---------------- Kernel 2: bf16 MFMA scores — 64-row tiles, 16.9KB LDS (R10-verified, 97us) ----------------
// key = bits(float(score+1000)) with low 7 mantissa bits = chunk position p (0..127).
// col = half*2048 + p*16 + lrow. Per-lane 8-deep sorted u32 lists (4 rows) -> TWO-PASS block merge
// (16KB scratch) -> top-12/half. bf16 score err + 0.008 trunc << rank8->12 margin; rerank exact fp64.
//
// Measured history (final structure selection):
//  R10: THIS kernel: VGPR 40, no spill, conflicts 0, knn 97us. Verified optimum of the structure.
//  R15: parity-split across 2048 blocks: per-block overheads (full-half staging, 32 barriers,
//       merge scans) scale with block count -> VALU work 2.3x, knn 248us. Block-splitting REJECTED.
//  R9/R14: 8 waves/SIMD -> allocator splits 64-reg budget ~32arch+32acc -> spill. REJECTED.
//  R4/R7: LDS dbuf + lgkm-only inner loop + XOR swizzle (conflicts 4.45M->0) retained verbatim.
__global__ __launch_bounds__(256, 6) void knn_cand_kernel(const unsigned short* __restrict__ xpack,
                                                          const float* __restrict__ xxn,
                                                          int* __restrict__ cand) {
    __shared__ __align__(16) unsigned int mK[4096];          // 16 KB: dbuf overlay / merge scratch
    __shared__ float xxs[128];                               // 2 x 64 norms (double-buffered)
    unsigned short* BUF0 = (unsigned short*)mK;              // 64 rows x 64 ushorts (8 KB, swizzled)
    unsigned short* BUF1 = BUF0 + 4096;                      // second buffer (8 KB)

    const int tid  = threadIdx.x;
    const int n0   = blockIdx.x * 64;
    const int half = blockIdx.y;
    const int b    = blockIdx.z;
    const int wave = tid >> 6;
    const int lane = tid & 63;
    const int lrow = lane & 15;
    const int quad = lane >> 4;
    const int colbase = half << 11;                          // first candidate row of this half

    const unsigned short* xp = xpack + ((size_t)b << 12) * 64;
    const float* xnn = xxn + (b << 12);

    // A fragments: direct global load (L2-resident, coalesced)
    const int arow = n0 + wave * 16 + lrow;
    short8 ah0 = *(const short8*)&xp[arow * 64 + quad * 8];
    short8 ah1 = *(const short8*)&xp[arow * 64 + 32 + quad * 8];

    unsigned int keys[4][8];
    #pragma unroll
    for (int r = 0; r < 4; ++r)
        #pragma unroll
        for (int j = 0; j < 8; ++j) keys[r][j] = 0u;

    uint4 pr[2]; float pxv;
    // staging geometry: 2 chunks/thread (64 rows x 8 chunks = 512 = 256 thr x 2);
    // chunk G -> row G>>3, slot (G&7)^(row&7) (XOR swizzle, verified conflict-free R7)
    int swi[2];
    #pragma unroll
    for (int k = 0; k < 2; ++k) {
        int G = k * 256 + tid, row = G >> 3, h = G & 7;
        swi[k] = row * 64 + ((h ^ (row & 7)) << 3);          // swizzled ushort index
    }

    // priming: tile 0 -> BUF0 + xxs[0]
    {
        const size_t base0 = (size_t)colbase * 64;
        #pragma unroll
        for (int k = 0; k < 2; ++k) {
            int G = k * 256 + tid;
            pr[k] = *(const uint4*)&xp[base0 + G * 8];
        }
        pxv = (tid < 64) ? xnn[colbase + tid] : 0.f;
        #pragma unroll
        for (int k = 0; k < 2; ++k)
            *(uint4*)&BUF0[swi[k]] = pr[k];
        if (tid < 64) xxs[tid] = pxv;
    }
    __syncthreads();

    for (int ot = 0; ot < 32; ++ot) {
        unsigned short* cur = (ot & 1) ? BUF1 : BUF0;
        unsigned short* nxt = (ot & 1) ? BUF0 : BUF1;
        const float*    xs  = xxs + (ot & 1) * 64;

        // a) issue loads for tile ot+1 (in flight during compute; no other VMEM in the loop)
        if (ot < 31) {
            const size_t base = (size_t)(colbase + (ot + 1) * 64) * 64;
            #pragma unroll
            for (int k = 0; k < 2; ++k) {
                int G = k * 256 + tid;
                pr[k] = *(const uint4*)&xp[base + G * 8];
            }
            if (tid < 64) pxv = xnn[colbase + (ot + 1) * 64 + tid];
        }

        // b) compute on cur (tile ot, 4 p2-steps) — LDS-only reads
        #pragma unroll
        for (int p2 = 0; p2 < 4; ++p2) {
            const int row0 = p2 * 16 + lrow;
            const int s    = lrow & 7;                       // row0&7 == lrow&7
            short8 bh0 = *(const short8*)&cur[row0 * 64 + ((quad ^ s) << 3)];
            short8 bh1 = *(const short8*)&cur[row0 * 64 + (((4 + quad) ^ s) << 3)];
            const float xm = xs[row0];
            f32x4 acc = {0.f, 0.f, 0.f, 0.f};
            acc = __builtin_amdgcn_mfma_f32_16x16x32_bf16(ah0, bh0, acc, 0, 0, 0);
            acc = __builtin_amdgcn_mfma_f32_16x16x32_bf16(ah1, bh1, acc, 0, 0, 0);
            const unsigned int pp = (unsigned int)(ot * 4 + p2);
            #pragma unroll
            for (int r = 0; r < 4; ++r) {
                float v = fmaf(acc[r], 2.f, xm);             // score + 1000 (>0)
                unsigned int t = (__float_as_uint(v) & 0xFFFFFF80u) | pp;
                // med3 insert: j descending so keys[j-1] is still the OLD value
                #pragma unroll
                for (int j = 7; j >= 1; --j)
                    keys[r][j] = umed3(keys[r][j - 1], keys[r][j], t);
                keys[r][0] = keys[r][0] > t ? keys[r][0] : t;
            }
        }

        // c) write prefetch into nxt (swizzled) BEFORE the barrier (pr not live across barrier)
        if (ot < 31) {
            #pragma unroll
            for (int k = 0; k < 2; ++k)
                *(uint4*)&nxt[swi[k]] = pr[k];
            if (tid < 64) xxs[(1 - (ot & 1)) * 64 + tid] = pxv;
        }
        // d) single barrier per tile
        __syncthreads();
    }

    // TWO-PASS merge in 16 KB scratch (exact top-12 is scan-order independent):
    // pass A: dump keys[r][0..3] -> mK16[row][lrow*4+j], scan 64; pass B: keys[r][4..7], scan 64.
    const int mrow = wave * 16 + quad * 4;

    unsigned int bk[NCH]; int bc[NCH];
    #pragma unroll
    for (int j = 0; j < NCH; ++j) { bk[j] = 0u; bc[j] = 0; }

    // pass A dump
    #pragma unroll
    for (int r = 0; r < 4; ++r) {
        uint4 k0 = make_uint4(keys[r][0], keys[r][1], keys[r][2], keys[r][3]);
        *(uint4*)&mK[(mrow + r) * 64 + lrow * 4] = k0;
    }
    __syncthreads();
    if (tid < 64) {
        const unsigned int* rowK = mK + tid * 64;
        for (int c = 0; c < 64; ++c) {
            int pos = (tid + c) & 63;
            unsigned int k = rowK[pos];
            if (k > bk[NCH - 1]) {
                int lr = pos >> 2;
                int p  = (int)(k & 0x7Fu);
                int col = (half << 11) + (p << 4) + lr;
                bk[NCH - 1] = k; bc[NCH - 1] = col;
                #pragma unroll
                for (int j = NCH - 1; j > 0; --j) {
                    if (bk[j] > bk[j - 1]) {
                        unsigned int tk = bk[j]; bk[j] = bk[j - 1]; bk[j - 1] = tk;
                        int tc = bc[j]; bc[j] = bc[j - 1]; bc[j - 1] = tc;
                    }
                }
            }
        }
    }
    __syncthreads();

    // pass B dump
    #pragma unroll
    for (int r = 0; r < 4; ++r) {
        uint4 k1 = make_uint4(keys[r][4], keys[r][5], keys[r][6], keys[r][7]);
        *(uint4*)&mK[(mrow + r) * 64 + lrow * 4] = k1;
    }
    __syncthreads();
    if (tid < 64) {
        const unsigned int* rowK = mK + tid * 64;
        for (int c = 0; c < 64; ++c) {
            int pos = (tid + c) & 63;
            unsigned int k = rowK[pos];
            if (k > bk[NCH - 1]) {
                int lr = pos >> 2;
                int p  = (int)(k & 0x7Fu);
                int col = (half << 11) + (p << 4) + lr;
                bk[NCH - 1] = k; bc[NCH - 1] = col;
                #pragma unroll
                for (int j = NCH - 1; j > 0; --j) {
                    if (bk[j] > bk[j - 1]) {
                        unsigned int tk = bk[j]; bk[j] = bk[j - 1]; bk[j - 1] = tk;
                        int tc = bc[j]; bc[j] = bc[j - 1]; bc[j - 1] = tc;
                    }
                }
            }
        }
        int* co = cand + ((size_t)((b << 12) + n0 + tid)) * NCT + half * NCH;
        #pragma unroll
        for (int j = 0; j < NCH; ++j) co[j] = bc[j];
    }
}

// ---------------- Kernel 3: exact fp64 re-rank (parallel ranking) + gather/max -> feat ----------------
__global__ __launch_bounds__(256) void rerank_kernel(const float* __restrict__ x,
                                                     const double* __restrict__ xxd,
                                                     const int* __restrict__ cand,
                                                     float* __restrict__ feat) {
    __shared__ double sc[4][NCT];
    __shared__ int    si[4][NCT];
    __shared__ int    sel[4][KNN];
    const int tid = threadIdx.x, wave = tid >> 6, lane = tid & 63;
    const size_t row = (size_t)blockIdx.x * 4 + wave;     // 0..32767
    const int b = (int)(row >> 12);
    const float* xb = x + (((size_t)b) << 12) * CIN;
    const float* xn = x + row * CIN;

    const int cidx = lane & 31, part = lane >> 5;
    if (cidx < NCT) {
        int m = cand[row * NCT + cidx];
        const float* xm = xb + (size_t)m * CIN;
        const float* xa = xn + part * 32;
        const float* xv = xm + part * 32;
        // 4 independent fp64 accumulators: breaks the 32-deep serial FMA chain
        double a0 = 0.0, a1 = 0.0, a2 = 0.0, a3 = 0.0;
        #pragma unroll
        for (int c4 = 0; c4 < 8; c4 += 4) {
            float4 p0 = *(const float4*)&xa[(c4 + 0) * 4];
            float4 q0 = *(const float4*)&xv[(c4 + 0) * 4];
            float4 p1 = *(const float4*)&xa[(c4 + 1) * 4];
            float4 q1 = *(const float4*)&xv[(c4 + 1) * 4];
            float4 p2 = *(const float4*)&xa[(c4 + 2) * 4];
            float4 q2 = *(const float4*)&xv[(c4 + 2) * 4];
            float4 p3 = *(const float4*)&xa[(c4 + 3) * 4];
            float4 q3 = *(const float4*)&xv[(c4 + 3) * 4];
            a0 = fma((double)p0.x, (double)q0.x, a0); a0 = fma((double)p0.y, (double)q0.y, a0);
            a0 = fma((double)p0.z, (double)q0.z, a0); a0 = fma((double)p0.w, (double)q0.w, a0);
            a1 = fma((double)p1.x, (double)q1.x, a1); a1 = fma((double)p1.y, (double)q1.y, a1);
            a1 = fma((double)p1.z, (double)q1.z, a1); a1 = fma((double)p1.w, (double)q1.w, a1);
            a2 = fma((double)p2.x, (double)q2.x, a2); a2 = fma((double)p2.y, (double)q2.y, a2);
            a2 = fma((double)p2.z, (double)q2.z, a2); a2 = fma((double)p2.w, (double)q2.w, a2);
            a3 = fma((double)p3.x, (double)q3.x, a3); a3 = fma((double)p3.y, (double)q3.y, a3);
            a3 = fma((double)p3.z, (double)q3.z, a3); a3 = fma((double)p3.w, (double)q3.w, a3);
        }
        double d = (a0 + a1) + (a2 + a3);
        d += __shfl_xor(d, 32);
        if (part == 0) {
            sc[wave][cidx] = 2.0 * d - xxd[(((size_t)b) << 12) + m];
            si[wave][cidx] = m;
        }
    }
    __syncthreads();

    // parallel exact ranking: lane i counts candidates strictly ahead of it
    if (lane < NCT) {
        double myv = sc[wave][lane];
        int    mym = si[wave][lane];
        int rank = 0;
        #pragma unroll
        for (int c = 0; c < NCT; ++c) {
            double v = sc[wave][c];
            int    m = si[wave][c];
            rank += (v > myv || (v == myv && m < mym)) ? 1 : 0;
        }
        if (rank < KNN) sel[wave][rank] = mym;
    }
    __syncthreads();

    float mx = -3.0e38f;
    #pragma unroll
    for (int j = 0; j < KNN; ++j)
        mx = fmaxf(mx, xb[(size_t)sel[wave][j] * CIN + lane]);
    feat[row * CIN + lane] = mx;
}

// ---------------- Kernel 4: conv (fp32 VALU) -> y + BN stats ----------------
// Channel-contiguous remap (R15-verified, ~20us saved): thread owns channels ch4..ch4+3
// (ch4=(tid&31)*4) -> W read = 1 ds_read_b128, Fs = float4 per 4 c-iters, y store = 1
// coalesced float4. Per-channel accumulation order (c ascending) unchanged -> identical numerics.
__global__ __launch_bounds__(256) void conv_stats_kernel(const float* __restrict__ feat,
                                                         const float* __restrict__ W,
                                                         float* __restrict__ y,
                                                         float* __restrict__ st) {
    __shared__ float Wt[64 * 128];   // Wt[c][o]
    __shared__ float Fs[64 * 64];
    __shared__ float bs[128], bs2[128];
    const int tid = threadIdx.x;
    const int n0  = blockIdx.x * 64;

    for (int i = tid; i < 8192; i += 256) {
        int o = i >> 6, c = i & 63;
        Wt[c * 128 + o] = W[i];
    }
    for (int i = tid; i < 1024; i += 256)
        ((float4*)Fs)[i] = ((const float4*)(feat + (size_t)n0 * CIN))[i];
    if (tid < 128) { bs[tid] = 0.f; bs2[tid] = 0.f; }
    __syncthreads();

    const int ch4 = (tid & 31) * 4, rg = tid >> 5;
    float ts[4] = {0.f, 0.f, 0.f, 0.f}, ts2[4] = {0.f, 0.f, 0.f, 0.f};
    #pragma unroll
    for (int p = 0; p < 4; ++p) {
        const int r0 = p * 16 + rg * 2;
        float acc0[4] = {0.f, 0.f, 0.f, 0.f}, acc1[4] = {0.f, 0.f, 0.f, 0.f};
        for (int c4 = 0; c4 < 16; ++c4) {
            float4 f0v = *(const float4*)&Fs[r0 * 64 + c4 * 4];
            float4 f1v = *(const float4*)&Fs[(r0 + 1) * 64 + c4 * 4];
            const float f0a[4] = {f0v.x, f0v.y, f0v.z, f0v.w};
            const float f1a[4] = {f1v.x, f1v.y, f1v.z, f1v.w};
            #pragma unroll
            for (int cc = 0; cc < 4; ++cc) {
                float4 w = *(const float4*)&Wt[(c4 * 4 + cc) * 128 + ch4];
                const float wa[4] = {w.x, w.y, w.z, w.w};
                #pragma unroll
                for (int j = 0; j < 4; ++j) {
                    acc0[j] += f0a[cc] * wa[j];
                    acc1[j] += f1a[cc] * wa[j];
                }
            }
        }
        *(float4*)&y[(size_t)(n0 + r0)     * COUT + ch4] = make_float4(acc0[0], acc0[1], acc0[2], acc0[3]);
        *(float4*)&y[(size_t)(n0 + r0 + 1) * COUT + ch4] = make_float4(acc1[0], acc1[1], acc1[2], acc1[3]);
        #pragma unroll
        for (int j = 0; j < 4; ++j) {
            ts[j]  += acc0[j] + acc1[j];
            ts2[j] += acc0[j] * acc0[j] + acc1[j] * acc1[j];
        }
    }
    #pragma unroll
    for (int j = 0; j < 4; ++j) {
        atomicAdd(&bs [ch4 + j], ts[j]);
        atomicAdd(&bs2[ch4 + j], ts2[j]);
    }
    __syncthreads();
    if (tid < 128) {
        atomicAdd(&st[tid],       bs[tid]);
        atomicAdd(&st[128 + tid], bs2[tid]);
    }
}

// ---------------- Kernel 5: elementwise BN + LeakyReLU -> fp32 out ----------------
__global__ __launch_bounds__(256) void norm_out_kernel(const float* __restrict__ y,
                                                       const float* __restrict__ st,
                                                       const float* __restrict__ gamma,
                                                       const float* __restrict__ beta,
                                                       float* __restrict__ out) {
    size_t i = ((size_t)blockIdx.x * 256 + threadIdx.x) * 4;
    int c0 = (int)(i & 127);
    float4 v = *(const float4*)&y[i];
    float o[4];
    const float inv = 1.0f / (float)TOTROWS;
    #pragma unroll
    for (int j = 0; j < 4; ++j) {
        int c = c0 + j;
        float m  = st[c] * inv;
        float vr = st[128 + c] * inv - m * m;
        float sc = rsqrtf(vr + 1e-5f) * gamma[c];
        float t  = (((const float*)&v)[j] - m) * sc + beta[c];
        o[j] = (t >= 0.f) ? t : 0.01f * t;
    }
    *(float4*)&out[i] = make_float4(o[0], o[1], o[2], o[3]);
}

extern "C" void kernel_launch(void* const* d_in, const int* in_sizes, int n_in,
                              void* d_out, int out_size, void* d_ws, size_t ws_size,
                              hipStream_t stream) {
    (void)in_sizes; (void)n_in; (void)out_size; (void)ws_size;
    const float* x     = (const float*)d_in[0];
    const float* W     = (const float*)d_in[1];
    const float* gamma = (const float*)d_in[2];
    const float* beta  = (const float*)d_in[3];
    // d_in[4] is k == 8 (compile-time KNN)
    float* out = (float*)d_out;

    // workspace (~28.4 MB): xxn 128K | xxd 256K | cand 4M | feat 8M | region 16M (xpack 4M, reused as y) | st
    char*   ws    = (char*)d_ws;
    float*  xxn   = (float*)ws;
    double* xxd   = (double*)(ws + 131072);
    int*    cand  = (int*)(ws + 131072 + 262144);
    float*  feat  = (float*)(ws + 131072 + 262144 + 4194304);
    unsigned short* xpack = (unsigned short*)(ws + 131072 + 262144 + 4194304 + 8388608);
    float*  y     = (float*)xpack;   // xpack (4 MB used) dead after knn_cand; y is 16 MB fp32
    float*  st    = (float*)(ws + 131072 + 262144 + 4194304 + 8388608 + 16777216);

    hipMemsetAsync(st, 0, 256 * sizeof(float), stream);
    prep_kernel      <<<TOTROWS * 8 / 256, 256, 0, stream>>>(x, xpack, xxn, xxd);
    knn_cand_kernel  <<<dim3(NPTS / 64, 2, BATCH), 256, 0, stream>>>(xpack, xxn, cand);
    rerank_kernel    <<<TOTROWS / 4, 256, 0, stream>>>(x, xxd, cand, feat);
    conv_stats_kernel<<<TOTROWS / 64, 256, 0, stream>>>(feat, W, y, st);
    norm_out_kernel  <<<(TOTROWS * COUT) / (256 * 4), 256, 0, stream>>>(y, st, gamma, beta, out);
}

// Round 18
// 243.228 us; speedup vs baseline: 1.5912x; 1.0053x over previous
//
#include <hip/hip_runtime.h>
#include <hip/hip_bf16.h>

#define NPTS 4096
#define CIN 64
#define COUT 128
#define BATCH 8
#define KNN 8
#define NCH 12              // candidates per column-half
#define NCT 24              // total candidates per row
#define TOTROWS (BATCH * NPTS)   // 32768

using short8 = __attribute__((ext_vector_type(8))) short;
using f32x4  = __attribute__((ext_vector_type(4))) float;

__device__ __forceinline__ unsigned short f2bf_rne(float f) {
    unsigned int u = __float_as_uint(f);
    unsigned int r = (u + 0x7fffu + ((u >> 16) & 1u)) >> 16;
    return (unsigned short)r;
}

// single-instruction median-of-3 (VOP3, gfx9+). Emit directly; backend matching
// from C min/max is not guaranteed.
__device__ __forceinline__ unsigned int umed3(unsigned int a, unsigned int b, unsigned int c) {
    unsigned int d;
    asm("v_med3_u32 %0, %1, %2, %3" : "=v"(d) : "v"(a), "v"(b), "v"(c));
    return d;
}

// ---------------- Kernel 1: pack x -> bf16(RNE) rows (128B) + norms (xxn = 1000-xx fp32, xxd fp64) ----------------
__global__ __launch_bounds__(256) void prep_kernel(const float* __restrict__ x,
                                                   unsigned short* __restrict__ xpack,
                                                   float* __restrict__ xxn,
                                                   double* __restrict__ xxd) {
    int i   = blockIdx.x * 256 + threadIdx.x;    // 0 .. 262143
    int row = i >> 3, g = i & 7;                 // 8 threads per row
    const float* src = x + (size_t)row * CIN + g * 8;
    float4 v0 = *(const float4*)src;
    float4 v1 = *(const float4*)(src + 4);
    float f[8] = {v0.x, v0.y, v0.z, v0.w, v1.x, v1.y, v1.z, v1.w};

    unsigned int h[8];
    double s = 0.0;
    #pragma unroll
    for (int j = 0; j < 8; ++j) {
        h[j] = (unsigned int)f2bf_rne(f[j]);
        s += (double)f[j] * (double)f[j];
    }
    uint4 hi;
    hi.x = h[0] | (h[1] << 16); hi.y = h[2] | (h[3] << 16);
    hi.z = h[4] | (h[5] << 16); hi.w = h[6] | (h[7] << 16);
    *(uint4*)&xpack[(size_t)row * 64 + g * 8] = hi;

    s += __shfl_xor(s, 1);
    s += __shfl_xor(s, 2);
    s += __shfl_xor(s, 4);
    if (g == 0) { xxn[row] = 1000.f - (float)s; xxd[row] = s; }
}

// ---------------- Kernel 2: bf16 MFMA scores — 64-row tiles, 16.9KB LDS + tail-skip insert ----------------
// key = bits(float(score+1000)) with low 7 mantissa bits = chunk position p (0..127).
// col = half*2048 + p*16 + lrow. Per-lane 8-deep sorted u32 lists (4 rows) -> TWO-PASS block merge
// (16KB scratch) -> top-12/half. bf16 score err + 0.008 trunc << rank8->12 margin; rerank exact fp64.
//
// Measured history (final structure selection):
//  R10/R16: THIS structure: VGPR 40, no spill, conflicts 0, knn 97us. Verified optimum.
//  R15: block-splitting (2048 blocks) -> per-block overheads 2.3x VALU. REJECTED.
//  R9/R14: 8 waves/SIMD -> allocator splits 64-reg budget -> spill. REJECTED.
//  R4/R7: LDS dbuf + lgkm-only inner loop + XOR swizzle retained verbatim.
// NEW (R17): tail-skip — insert only if __any(t > keys[r][7]). Wave-uniform branch; a pair
// changes the list iff t exceeds the current minimum, and med3 with smaller t is a no-op,
// so skipping is EXACT. P(any-lane-insert) ~ 1-(1-8/c)^64 -> ~40% of inserts skipped.
__global__ __launch_bounds__(256, 6) void knn_cand_kernel(const unsigned short* __restrict__ xpack,
                                                          const float* __restrict__ xxn,
                                                          int* __restrict__ cand) {
    __shared__ __align__(16) unsigned int mK[4096];          // 16 KB: dbuf overlay / merge scratch
    __shared__ float xxs[128];                               // 2 x 64 norms (double-buffered)
    unsigned short* BUF0 = (unsigned short*)mK;              // 64 rows x 64 ushorts (8 KB, swizzled)
    unsigned short* BUF1 = BUF0 + 4096;                      // second buffer (8 KB)

    const int tid  = threadIdx.x;
    const int n0   = blockIdx.x * 64;
    const int half = blockIdx.y;
    const int b    = blockIdx.z;
    const int wave = tid >> 6;
    const int lane = tid & 63;
    const int lrow = lane & 15;
    const int quad = lane >> 4;
    const int colbase = half << 11;                          // first candidate row of this half

    const unsigned short* xp = xpack + ((size_t)b << 12) * 64;
    const float* xnn = xxn + (b << 12);

    // A fragments: direct global load (L2-resident, coalesced)
    const int arow = n0 + wave * 16 + lrow;
    short8 ah0 = *(const short8*)&xp[arow * 64 + quad * 8];
    short8 ah1 = *(const short8*)&xp[arow * 64 + 32 + quad * 8];

    unsigned int keys[4][8];
    #pragma unroll
    for (int r = 0; r < 4; ++r)
        #pragma unroll
        for (int j = 0; j < 8; ++j) keys[r][j] = 0u;

    uint4 pr[2]; float pxv;
    // staging geometry: 2 chunks/thread (64 rows x 8 chunks = 512 = 256 thr x 2);
    // chunk G -> row G>>3, slot (G&7)^(row&7) (XOR swizzle, verified conflict-free R7)
    int swi[2];
    #pragma unroll
    for (int k = 0; k < 2; ++k) {
        int G = k * 256 + tid, row = G >> 3, h = G & 7;
        swi[k] = row * 64 + ((h ^ (row & 7)) << 3);          // swizzled ushort index
    }

    // priming: tile 0 -> BUF0 + xxs[0]
    {
        const size_t base0 = (size_t)colbase * 64;
        #pragma unroll
        for (int k = 0; k < 2; ++k) {
            int G = k * 256 + tid;
            pr[k] = *(const uint4*)&xp[base0 + G * 8];
        }
        pxv = (tid < 64) ? xnn[colbase + tid] : 0.f;
        #pragma unroll
        for (int k = 0; k < 2; ++k)
            *(uint4*)&BUF0[swi[k]] = pr[k];
        if (tid < 64) xxs[tid] = pxv;
    }
    __syncthreads();

    for (int ot = 0; ot < 32; ++ot) {
        unsigned short* cur = (ot & 1) ? BUF1 : BUF0;
        unsigned short* nxt = (ot & 1) ? BUF0 : BUF1;
        const float*    xs  = xxs + (ot & 1) * 64;

        // a) issue loads for tile ot+1 (in flight during compute; no other VMEM in the loop)
        if (ot < 31) {
            const size_t base = (size_t)(colbase + (ot + 1) * 64) * 64;
            #pragma unroll
            for (int k = 0; k < 2; ++k) {
                int G = k * 256 + tid;
                pr[k] = *(const uint4*)&xp[base + G * 8];
            }
            if (tid < 64) pxv = xnn[colbase + (ot + 1) * 64 + tid];
        }

        // b) compute on cur (tile ot, 4 p2-steps) — LDS-only reads
        #pragma unroll
        for (int p2 = 0; p2 < 4; ++p2) {
            const int row0 = p2 * 16 + lrow;
            const int s    = lrow & 7;                       // row0&7 == lrow&7
            short8 bh0 = *(const short8*)&cur[row0 * 64 + ((quad ^ s) << 3)];
            short8 bh1 = *(const short8*)&cur[row0 * 64 + (((4 + quad) ^ s) << 3)];
            const float xm = xs[row0];
            f32x4 acc = {0.f, 0.f, 0.f, 0.f};
            acc = __builtin_amdgcn_mfma_f32_16x16x32_bf16(ah0, bh0, acc, 0, 0, 0);
            acc = __builtin_amdgcn_mfma_f32_16x16x32_bf16(ah1, bh1, acc, 0, 0, 0);
            const unsigned int pp = (unsigned int)(ot * 4 + p2);
            #pragma unroll
            for (int r = 0; r < 4; ++r) {
                float v = fmaf(acc[r], 2.f, xm);             // score + 1000 (>0)
                unsigned int t = (__float_as_uint(v) & 0xFFFFFF80u) | pp;
                // tail-skip: list changes iff t > current min (keys[r][7]); med3 with
                // smaller t is a no-op, so the skip is exact. Wave-uniform branch.
                if (__any(t > keys[r][7])) {
                    // med3 insert: j descending so keys[j-1] is still the OLD value
                    #pragma unroll
                    for (int j = 7; j >= 1; --j)
                        keys[r][j] = umed3(keys[r][j - 1], keys[r][j], t);
                    keys[r][0] = keys[r][0] > t ? keys[r][0] : t;
                }
            }
        }

        // c) write prefetch into nxt (swizzled) BEFORE the barrier (pr not live across barrier)
        if (ot < 31) {
            #pragma unroll
            for (int k = 0; k < 2; ++k)
                *(uint4*)&nxt[swi[k]] = pr[k];
            if (tid < 64) xxs[(1 - (ot & 1)) * 64 + tid] = pxv;
        }
        // d) single barrier per tile
        __syncthreads();
    }

    // TWO-PASS merge in 16 KB scratch (exact top-12 is scan-order independent):
    // pass A: dump keys[r][0..3] -> mK16[row][lrow*4+j], scan 64; pass B: keys[r][4..7], scan 64.
    const int mrow = wave * 16 + quad * 4;

    unsigned int bk[NCH]; int bc[NCH];
    #pragma unroll
    for (int j = 0; j < NCH; ++j) { bk[j] = 0u; bc[j] = 0; }

    // pass A dump
    #pragma unroll
    for (int r = 0; r < 4; ++r) {
        uint4 k0 = make_uint4(keys[r][0], keys[r][1], keys[r][2], keys[r][3]);
        *(uint4*)&mK[(mrow + r) * 64 + lrow * 4] = k0;
    }
    __syncthreads();
    if (tid < 64) {
        const unsigned int* rowK = mK + tid * 64;
        for (int c = 0; c < 64; ++c) {
            int pos = (tid + c) & 63;
            unsigned int k = rowK[pos];
            if (k > bk[NCH - 1]) {
                int lr = pos >> 2;
                int p  = (int)(k & 0x7Fu);
                int col = (half << 11) + (p << 4) + lr;
                bk[NCH - 1] = k; bc[NCH - 1] = col;
                #pragma unroll
                for (int j = NCH - 1; j > 0; --j) {
                    if (bk[j] > bk[j - 1]) {
                        unsigned int tk = bk[j]; bk[j] = bk[j - 1]; bk[j - 1] = tk;
                        int tc = bc[j]; bc[j] = bc[j - 1]; bc[j - 1] = tc;
                    }
                }
            }
        }
    }
    __syncthreads();

    // pass B dump
    #pragma unroll
    for (int r = 0; r < 4; ++r) {
        uint4 k1 = make_uint4(keys[r][4], keys[r][5], keys[r][6], keys[r][7]);
        *(uint4*)&mK[(mrow + r) * 64 + lrow * 4] = k1;
    }
    __syncthreads();
    if (tid < 64) {
        const unsigned int* rowK = mK + tid * 64;
        for (int c = 0; c < 64; ++c) {
            int pos = (tid + c) & 63;
            unsigned int k = rowK[pos];
            if (k > bk[NCH - 1]) {
                int lr = pos >> 2;
                int p  = (int)(k & 0x7Fu);
                int col = (half << 11) + (p << 4) + lr;
                bk[NCH - 1] = k; bc[NCH - 1] = col;
                #pragma unroll
                for (int j = NCH - 1; j > 0; --j) {
                    if (bk[j] > bk[j - 1]) {
                        unsigned int tk = bk[j]; bk[j] = bk[j - 1]; bk[j - 1] = tk;
                        int tc = bc[j]; bc[j] = bc[j - 1]; bc[j - 1] = tc;
                    }
                }
            }
        }
        int* co = cand + ((size_t)((b << 12) + n0 + tid)) * NCT + half * NCH;
        #pragma unroll
        for (int j = 0; j < NCH; ++j) co[j] = bc[j];
    }
}

// ---------------- Kernel 3: exact fp64 re-rank (parallel ranking) + gather/max -> feat ----------------
__global__ __launch_bounds__(256) void rerank_kernel(const float* __restrict__ x,
                                                     const double* __restrict__ xxd,
                                                     const int* __restrict__ cand,
                                                     float* __restrict__ feat) {
    __shared__ double sc[4][NCT];
    __shared__ int    si[4][NCT];
    __shared__ int    sel[4][KNN];
    const int tid = threadIdx.x, wave = tid >> 6, lane = tid & 63;
    const size_t row = (size_t)blockIdx.x * 4 + wave;     // 0..32767
    const int b = (int)(row >> 12);
    const float* xb = x + (((size_t)b) << 12) * CIN;
    const float* xn = x + row * CIN;

    const int cidx = lane & 31, part = lane >> 5;
    if (cidx < NCT) {
        int m = cand[row * NCT + cidx];
        const float* xm = xb + (size_t)m * CIN;
        const float* xa = xn + part * 32;
        const float* xv = xm + part * 32;
        // 4 independent fp64 accumulators: breaks the 32-deep serial FMA chain
        double a0 = 0.0, a1 = 0.0, a2 = 0.0, a3 = 0.0;
        #pragma unroll
        for (int c4 = 0; c4 < 8; c4 += 4) {
            float4 p0 = *(const float4*)&xa[(c4 + 0) * 4];
            float4 q0 = *(const float4*)&xv[(c4 + 0) * 4];
            float4 p1 = *(const float4*)&xa[(c4 + 1) * 4];
            float4 q1 = *(const float4*)&xv[(c4 + 1) * 4];
            float4 p2 = *(const float4*)&xa[(c4 + 2) * 4];
            float4 q2 = *(const float4*)&xv[(c4 + 2) * 4];
            float4 p3 = *(const float4*)&xa[(c4 + 3) * 4];
            float4 q3 = *(const float4*)&xv[(c4 + 3) * 4];
            a0 = fma((double)p0.x, (double)q0.x, a0); a0 = fma((double)p0.y, (double)q0.y, a0);
            a0 = fma((double)p0.z, (double)q0.z, a0); a0 = fma((double)p0.w, (double)q0.w, a0);
            a1 = fma((double)p1.x, (double)q1.x, a1); a1 = fma((double)p1.y, (double)q1.y, a1);
            a1 = fma((double)p1.z, (double)q1.z, a1); a1 = fma((double)p1.w, (double)q1.w, a1);
            a2 = fma((double)p2.x, (double)q2.x, a2); a2 = fma((double)p2.y, (double)q2.y, a2);
            a2 = fma((double)p2.z, (double)q2.z, a2); a2 = fma((double)p2.w, (double)q2.w, a2);
            a3 = fma((double)p3.x, (double)q3.x, a3); a3 = fma((double)p3.y, (double)q3.y, a3);
            a3 = fma((double)p3.z, (double)q3.z, a3); a3 = fma((double)p3.w, (double)q3.w, a3);
        }
        double d = (a0 + a1) + (a2 + a3);
        d += __shfl_xor(d, 32);
        if (part == 0) {
            sc[wave][cidx] = 2.0 * d - xxd[(((size_t)b) << 12) + m];
            si[wave][cidx] = m;
        }
    }
    __syncthreads();

    // parallel exact ranking: lane i counts candidates strictly ahead of it
    if (lane < NCT) {
        double myv = sc[wave][lane];
        int    mym = si[wave][lane];
        int rank = 0;
        #pragma unroll
        for (int c = 0; c < NCT; ++c) {
            double v = sc[wave][c];
            int    m = si[wave][c];
            rank += (v > myv || (v == myv && m < mym)) ? 1 : 0;
        }
        if (rank < KNN) sel[wave][rank] = mym;
    }
    __syncthreads();

    float mx = -3.0e38f;
    #pragma unroll
    for (int j = 0; j < KNN; ++j)
        mx = fmaxf(mx, xb[(size_t)sel[wave][j] * CIN + lane]);
    feat[row * CIN + lane] = mx;
}

// ---------------- Kernel 4: conv (fp32 VALU) -> y + BN stats ----------------
// Channel-contiguous remap (R15-verified): thread owns channels ch4..ch4+3 (ch4=(tid&31)*4) ->
// W read = 1 ds_read_b128, Fs = float4 per 4 c-iters, y store = 1 coalesced float4.
// NEW (R17): Wt pitch 128 -> 132. Pitch-128 staging writes put every lane on bank o%32
// (32-way conflict x 32 writes/thread). Pitch 132 + float4 global loads + (c,o) write
// interleave -> ~2-way (free). Compute float4 reads stay 16B-aligned (132%4==0) and
// sequential-per-lane (conflict-free). Accumulation order unchanged -> identical numerics.
__global__ __launch_bounds__(256) void conv_stats_kernel(const float* __restrict__ feat,
                                                         const float* __restrict__ W,
                                                         float* __restrict__ y,
                                                         float* __restrict__ st) {
    __shared__ float Wt[64 * 132];   // Wt[c][o], pitch 132
    __shared__ float Fs[64 * 64];
    __shared__ float bs[128], bs2[128];
    const int tid = threadIdx.x;
    const int n0  = blockIdx.x * 64;

    #pragma unroll
    for (int k = 0; k < 8; ++k) {
        int i4 = k * 256 + tid;          // float4 chunk 0..2047 of W (8192 floats)
        float4 w4 = ((const float4*)W)[i4];
        int o = i4 >> 4;                 // output channel (row of W)
        int c = (i4 & 15) * 4;           // input-channel group
        Wt[(c + 0) * 132 + o] = w4.x;
        Wt[(c + 1) * 132 + o] = w4.y;
        Wt[(c + 2) * 132 + o] = w4.z;
        Wt[(c + 3) * 132 + o] = w4.w;
    }
    for (int i = tid; i < 1024; i += 256)
        ((float4*)Fs)[i] = ((const float4*)(feat + (size_t)n0 * CIN))[i];
    if (tid < 128) { bs[tid] = 0.f; bs2[tid] = 0.f; }
    __syncthreads();

    const int ch4 = (tid & 31) * 4, rg = tid >> 5;
    float ts[4] = {0.f, 0.f, 0.f, 0.f}, ts2[4] = {0.f, 0.f, 0.f, 0.f};
    #pragma unroll
    for (int p = 0; p < 4; ++p) {
        const int r0 = p * 16 + rg * 2;
        float acc0[4] = {0.f, 0.f, 0.f, 0.f}, acc1[4] = {0.f, 0.f, 0.f, 0.f};
        for (int c4 = 0; c4 < 16; ++c4) {
            float4 f0v = *(const float4*)&Fs[r0 * 64 + c4 * 4];
            float4 f1v = *(const float4*)&Fs[(r0 + 1) * 64 + c4 * 4];
            const float f0a[4] = {f0v.x, f0v.y, f0v.z, f0v.w};
            const float f1a[4] = {f1v.x, f1v.y, f1v.z, f1v.w};
            #pragma unroll
            for (int cc = 0; cc < 4; ++cc) {
                float4 w = *(const float4*)&Wt[(c4 * 4 + cc) * 132 + ch4];
                const float wa[4] = {w.x, w.y, w.z, w.w};
                #pragma unroll
                for (int j = 0; j < 4; ++j) {
                    acc0[j] += f0a[cc] * wa[j];
                    acc1[j] += f1a[cc] * wa[j];
                }
            }
        }
        *(float4*)&y[(size_t)(n0 + r0)     * COUT + ch4] = make_float4(acc0[0], acc0[1], acc0[2], acc0[3]);
        *(float4*)&y[(size_t)(n0 + r0 + 1) * COUT + ch4] = make_float4(acc1[0], acc1[1], acc1[2], acc1[3]);
        #pragma unroll
        for (int j = 0; j < 4; ++j) {
            ts[j]  += acc0[j] + acc1[j];
            ts2[j] += acc0[j] * acc0[j] + acc1[j] * acc1[j];
        }
    }
    #pragma unroll
    for (int j = 0; j < 4; ++j) {
        atomicAdd(&bs [ch4 + j], ts[j]);
        atomicAdd(&bs2[ch4 + j], ts2[j]);
    }
    __syncthreads();
    if (tid < 128) {
        atomicAdd(&st[tid],       bs[tid]);
        atomicAdd(&st[128 + tid], bs2[tid]);
    }
}

// ---------------- Kernel 5: elementwise BN + LeakyReLU -> fp32 out ----------------
__global__ __launch_bounds__(256) void norm_out_kernel(const float* __restrict__ y,
                                                       const float* __restrict__ st,
                                                       const float* __restrict__ gamma,
                                                       const float* __restrict__ beta,
                                                       float* __restrict__ out) {
    size_t i = ((size_t)blockIdx.x * 256 + threadIdx.x) * 4;
    int c0 = (int)(i & 127);
    float4 v = *(const float4*)&y[i];
    float o[4];
    const float inv = 1.0f / (float)TOTROWS;
    #pragma unroll
    for (int j = 0; j < 4; ++j) {
        int c = c0 + j;
        float m  = st[c] * inv;
        float vr = st[128 + c] * inv - m * m;
        float sc = rsqrtf(vr + 1e-5f) * gamma[c];
        float t  = (((const float*)&v)[j] - m) * sc + beta[c];
        o[j] = (t >= 0.f) ? t : 0.01f * t;
    }
    *(float4*)&out[i] = make_float4(o[0], o[1], o[2], o[3]);
}

extern "C" void kernel_launch(void* const* d_in, const int* in_sizes, int n_in,
                              void* d_out, int out_size, void* d_ws, size_t ws_size,
                              hipStream_t stream) {
    (void)in_sizes; (void)n_in; (void)out_size; (void)ws_size;
    const float* x     = (const float*)d_in[0];
    const float* W     = (const float*)d_in[1];
    const float* gamma = (const float*)d_in[2];
    const float* beta  = (const float*)d_in[3];
    // d_in[4] is k == 8 (compile-time KNN)
    float* out = (float*)d_out;

    // workspace (~28.4 MB): xxn 128K | xxd 256K | cand 4M | feat 8M | region 16M (xpack 4M, reused as y) | st
    char*   ws    = (char*)d_ws;
    float*  xxn   = (float*)ws;
    double* xxd   = (double*)(ws + 131072);
    int*    cand  = (int*)(ws + 131072 + 262144);
    float*  feat  = (float*)(ws + 131072 + 262144 + 4194304);
    unsigned short* xpack = (unsigned short*)(ws + 131072 + 262144 + 4194304 + 8388608);
    float*  y     = (float*)xpack;   // xpack (4 MB used) dead after knn_cand; y is 16 MB fp32
    float*  st    = (float*)(ws + 131072 + 262144 + 4194304 + 8388608 + 16777216);

    hipMemsetAsync(st, 0, 256 * sizeof(float), stream);
    prep_kernel      <<<TOTROWS * 8 / 256, 256, 0, stream>>>(x, xpack, xxn, xxd);
    knn_cand_kernel  <<<dim3(NPTS / 64, 2, BATCH), 256, 0, stream>>>(xpack, xxn, cand);
    rerank_kernel    <<<TOTROWS / 4, 256, 0, stream>>>(x, xxd, cand, feat);
    conv_stats_kernel<<<TOTROWS / 64, 256, 0, stream>>>(feat, W, y, st);
    norm_out_kernel  <<<(TOTROWS * COUT) / (256 * 4), 256, 0, stream>>>(y, st, gamma, beta, out);
}

// Round 20
// 241.467 us; speedup vs baseline: 1.6028x; 1.0073x over previous
//
#include <hip/hip_runtime.h>
#include <hip/hip_bf16.h>

#define NPTS 4096
#define CIN 64
#define COUT 128
#define BATCH 8
#define KNN 8
#define NCH 12              // candidates per column-half
#define NCT 24              // total candidates per row
#define TOTROWS (BATCH * NPTS)   // 32768

using short8 = __attribute__((ext_vector_type(8))) short;
using f32x4  = __attribute__((ext_vector_type(4))) float;

__device__ __forceinline__ unsigned short f2bf_rne(float f) {
    unsigned int u = __float_as_uint(f);
    unsigned int r = (u + 0x7fffu + ((u >> 16) & 1u)) >> 16;
    return (unsigned short)r;
}

// single-instruction median-of-3 (VOP3, gfx9+). Emit directly; backend matching
// from C min/max is not guaranteed.
__device__ __forceinline__ unsigned int umed3(unsigned int a, unsigned int b, unsigned int c) {
    unsigned int d;
    asm("v_med3_u32 %0, %1, %2, %3" : "=v"(d) : "v"(a), "v"(b), "v"(c));
    return d;
}

// ---------------- Kernel 1: pack x -> bf16(RNE) rows (128B) + norms (xxn = 1000-xx fp32, xxd fp64) ----------------
__global__ __launch_bounds__(256) void prep_kernel(const float* __restrict__ x,
                                                   unsigned short* __restrict__ xpack,
                                                   float* __restrict__ xxn,
                                                   double* __restrict__ xxd) {
    int i   = blockIdx.x * 256 + threadIdx.x;    // 0 .. 262143
    int row = i >> 3, g = i & 7;                 // 8 threads per row
    const float* src = x + (size_t)row * CIN + g * 8;
    float4 v0 = *(const float4*)src;
    float4 v1 = *(const float4*)(src + 4);
    float f[8] = {v0.x, v0.y, v0.z, v0.w, v1.x, v1.y, v1.z, v1.w};

    unsigned int h[8];
    double s = 0.0;
    #pragma unroll
    for (int j = 0; j < 8; ++j) {
        h[j] = (unsigned int)f2bf_rne(f[j]);
        s += (double)f[j] * (double)f[j];
    }
    uint4 hi;
    hi.x = h[0] | (h[1] << 16); hi.y = h[2] | (h[3] << 16);
    hi.z = h[4] | (h[5] << 16); hi.w = h[6] | (h[7] << 16);
    *(uint4*)&xpack[(size_t)row * 64 + g * 8] = hi;

    s += __shfl_xor(s, 1);
    s += __shfl_xor(s, 2);
    s += __shfl_xor(s, 4);
    if (g == 0) { xxn[row] = 1000.f - (float)s; xxd[row] = s; }
}

// ---------------- Kernel 2: bf16 MFMA scores — 64-row tiles, 16.9KB LDS (R16-verified, 97us) ----------------
// key = bits(float(score+1000)) with low 7 mantissa bits = chunk position p (0..127).
// col = half*2048 + p*16 + lrow. Per-lane 8-deep sorted u32 lists (4 rows) -> TWO-PASS block merge
// (16KB scratch) -> top-12/half. bf16 score err + 0.008 trunc << rank8->12 margin; rerank exact fp64.
//
// Measured structure map (all rejected alternatives):
//  R4:  no-LDS global B-streaming -> L1/L2 latency on critical path, 188us. REJECTED.
//  R9/R14: 8 waves/SIMD -> allocator splits 64-reg unified budget ~32arch+32acc -> spill. REJECTED.
//  R15: block-splitting (2048 blocks) -> per-block overheads 2.3x VALU, 248us. REJECTED.
//  R18: __any tail-skip on med3 insert -> check overhead ~ saved work + broke scheduling,
//       97->100us. REJECTED (reverted here).
//  R7 swizzle (conflicts 4.45M->0) + lgkm-only inner loop + reg-prefetch dbuf retained.
__global__ __launch_bounds__(256, 6) void knn_cand_kernel(const unsigned short* __restrict__ xpack,
                                                          const float* __restrict__ xxn,
                                                          int* __restrict__ cand) {
    __shared__ __align__(16) unsigned int mK[4096];          // 16 KB: dbuf overlay / merge scratch
    __shared__ float xxs[128];                               // 2 x 64 norms (double-buffered)
    unsigned short* BUF0 = (unsigned short*)mK;              // 64 rows x 64 ushorts (8 KB, swizzled)
    unsigned short* BUF1 = BUF0 + 4096;                      // second buffer (8 KB)

    const int tid  = threadIdx.x;
    const int n0   = blockIdx.x * 64;
    const int half = blockIdx.y;
    const int b    = blockIdx.z;
    const int wave = tid >> 6;
    const int lane = tid & 63;
    const int lrow = lane & 15;
    const int quad = lane >> 4;
    const int colbase = half << 11;                          // first candidate row of this half

    const unsigned short* xp = xpack + ((size_t)b << 12) * 64;
    const float* xnn = xxn + (b << 12);

    // A fragments: direct global load (L2-resident, coalesced)
    const int arow = n0 + wave * 16 + lrow;
    short8 ah0 = *(const short8*)&xp[arow * 64 + quad * 8];
    short8 ah1 = *(const short8*)&xp[arow * 64 + 32 + quad * 8];

    unsigned int keys[4][8];
    #pragma unroll
    for (int r = 0; r < 4; ++r)
        #pragma unroll
        for (int j = 0; j < 8; ++j) keys[r][j] = 0u;

    uint4 pr[2]; float pxv;
    // staging geometry: 2 chunks/thread (64 rows x 8 chunks = 512 = 256 thr x 2);
    // chunk G -> row G>>3, slot (G&7)^(row&7) (XOR swizzle, verified conflict-free R7)
    int swi[2];
    #pragma unroll
    for (int k = 0; k < 2; ++k) {
        int G = k * 256 + tid, row = G >> 3, h = G & 7;
        swi[k] = row * 64 + ((h ^ (row & 7)) << 3);          // swizzled ushort index
    }

    // priming: tile 0 -> BUF0 + xxs[0]
    {
        const size_t base0 = (size_t)colbase * 64;
        #pragma unroll
        for (int k = 0; k < 2; ++k) {
            int G = k * 256 + tid;
            pr[k] = *(const uint4*)&xp[base0 + G * 8];
        }
        pxv = (tid < 64) ? xnn[colbase + tid] : 0.f;
        #pragma unroll
        for (int k = 0; k < 2; ++k)
            *(uint4*)&BUF0[swi[k]] = pr[k];
        if (tid < 64) xxs[tid] = pxv;
    }
    __syncthreads();

    for (int ot = 0; ot < 32; ++ot) {
        unsigned short* cur = (ot & 1) ? BUF1 : BUF0;
        unsigned short* nxt = (ot & 1) ? BUF0 : BUF1;
        const float*    xs  = xxs + (ot & 1) * 64;

        // a) issue loads for tile ot+1 (in flight during compute; no other VMEM in the loop)
        if (ot < 31) {
            const size_t base = (size_t)(colbase + (ot + 1) * 64) * 64;
            #pragma unroll
            for (int k = 0; k < 2; ++k) {
                int G = k * 256 + tid;
                pr[k] = *(const uint4*)&xp[base + G * 8];
            }
            if (tid < 64) pxv = xnn[colbase + (ot + 1) * 64 + tid];
        }

        // b) compute on cur (tile ot, 4 p2-steps) — LDS-only reads
        #pragma unroll
        for (int p2 = 0; p2 < 4; ++p2) {
            const int row0 = p2 * 16 + lrow;
            const int s    = lrow & 7;                       // row0&7 == lrow&7
            short8 bh0 = *(const short8*)&cur[row0 * 64 + ((quad ^ s) << 3)];
            short8 bh1 = *(const short8*)&cur[row0 * 64 + (((4 + quad) ^ s) << 3)];
            const float xm = xs[row0];
            f32x4 acc = {0.f, 0.f, 0.f, 0.f};
            acc = __builtin_amdgcn_mfma_f32_16x16x32_bf16(ah0, bh0, acc, 0, 0, 0);
            acc = __builtin_amdgcn_mfma_f32_16x16x32_bf16(ah1, bh1, acc, 0, 0, 0);
            const unsigned int pp = (unsigned int)(ot * 4 + p2);
            #pragma unroll
            for (int r = 0; r < 4; ++r) {
                float v = fmaf(acc[r], 2.f, xm);             // score + 1000 (>0)
                unsigned int t = (__float_as_uint(v) & 0xFFFFFF80u) | pp;
                // med3 insert: j descending so keys[j-1] is still the OLD value
                #pragma unroll
                for (int j = 7; j >= 1; --j)
                    keys[r][j] = umed3(keys[r][j - 1], keys[r][j], t);
                keys[r][0] = keys[r][0] > t ? keys[r][0] : t;
            }
        }

        // c) write prefetch into nxt (swizzled) BEFORE the barrier (pr not live across barrier)
        if (ot < 31) {
            #pragma unroll
            for (int k = 0; k < 2; ++k)
                *(uint4*)&nxt[swi[k]] = pr[k];
            if (tid < 64) xxs[(1 - (ot & 1)) * 64 + tid] = pxv;
        }
        // d) single barrier per tile
        __syncthreads();
    }

    // TWO-PASS merge in 16 KB scratch (exact top-12 is scan-order independent):
    // pass A: dump keys[r][0..3] -> mK16[row][lrow*4+j], scan 64; pass B: keys[r][4..7], scan 64.
    const int mrow = wave * 16 + quad * 4;

    unsigned int bk[NCH]; int bc[NCH];
    #pragma unroll
    for (int j = 0; j < NCH; ++j) { bk[j] = 0u; bc[j] = 0; }

    // pass A dump
    #pragma unroll
    for (int r = 0; r < 4; ++r) {
        uint4 k0 = make_uint4(keys[r][0], keys[r][1], keys[r][2], keys[r][3]);
        *(uint4*)&mK[(mrow + r) * 64 + lrow * 4] = k0;
    }
    __syncthreads();
    if (tid < 64) {
        const unsigned int* rowK = mK + tid * 64;
        for (int c = 0; c < 64; ++c) {
            int pos = (tid + c) & 63;
            unsigned int k = rowK[pos];
            if (k > bk[NCH - 1]) {
                int lr = pos >> 2;
                int p  = (int)(k & 0x7Fu);
                int col = (half << 11) + (p << 4) + lr;
                bk[NCH - 1] = k; bc[NCH - 1] = col;
                #pragma unroll
                for (int j = NCH - 1; j > 0; --j) {
                    if (bk[j] > bk[j - 1]) {
                        unsigned int tk = bk[j]; bk[j] = bk[j - 1]; bk[j - 1] = tk;
                        int tc = bc[j]; bc[j] = bc[j - 1]; bc[j - 1] = tc;
                    }
                }
            }
        }
    }
    __syncthreads();

    // pass B dump
    #pragma unroll
    for (int r = 0; r < 4; ++r) {
        uint4 k1 = make_uint4(keys[r][4], keys[r][5], keys[r][6], keys[r][7]);
        *(uint4*)&mK[(mrow + r) * 64 + lrow * 4] = k1;
    }
    __syncthreads();
    if (tid < 64) {
        const unsigned int* rowK = mK + tid * 64;
        for (int c = 0; c < 64; ++c) {
            int pos = (tid + c) & 63;
            unsigned int k = rowK[pos];
            if (k > bk[NCH - 1]) {
                int lr = pos >> 2;
                int p  = (int)(k & 0x7Fu);
                int col = (half << 11) + (p << 4) + lr;
                bk[NCH - 1] = k; bc[NCH - 1] = col;
                #pragma unroll
                for (int j = NCH - 1; j > 0; --j) {
                    if (bk[j] > bk[j - 1]) {
                        unsigned int tk = bk[j]; bk[j] = bk[j - 1]; bk[j - 1] = tk;
                        int tc = bc[j]; bc[j] = bc[j - 1]; bc[j - 1] = tc;
                    }
                }
            }
        }
        int* co = cand + ((size_t)((b << 12) + n0 + tid)) * NCT + half * NCH;
        #pragma unroll
        for (int j = 0; j < NCH; ++j) co[j] = bc[j];
    }
}

// ---------------- Kernel 3: exact fp64 re-rank (parallel ranking) + gather/max -> feat ----------------
__global__ __launch_bounds__(256) void rerank_kernel(const float* __restrict__ x,
                                                     const double* __restrict__ xxd,
                                                     const int* __restrict__ cand,
                                                     float* __restrict__ feat) {
    __shared__ double sc[4][NCT];
    __shared__ int    si[4][NCT];
    __shared__ int    sel[4][KNN];
    const int tid = threadIdx.x, wave = tid >> 6, lane = tid & 63;
    const size_t row = (size_t)blockIdx.x * 4 + wave;     // 0..32767
    const int b = (int)(row >> 12);
    const float* xb = x + (((size_t)b) << 12) * CIN;
    const float* xn = x + row * CIN;

    const int cidx = lane & 31, part = lane >> 5;
    if (cidx < NCT) {
        int m = cand[row * NCT + cidx];
        const float* xm = xb + (size_t)m * CIN;
        const float* xa = xn + part * 32;
        const float* xv = xm + part * 32;
        // 4 independent fp64 accumulators: breaks the 32-deep serial FMA chain
        double a0 = 0.0, a1 = 0.0, a2 = 0.0, a3 = 0.0;
        #pragma unroll
        for (int c4 = 0; c4 < 8; c4 += 4) {
            float4 p0 = *(const float4*)&xa[(c4 + 0) * 4];
            float4 q0 = *(const float4*)&xv[(c4 + 0) * 4];
            float4 p1 = *(const float4*)&xa[(c4 + 1) * 4];
            float4 q1 = *(const float4*)&xv[(c4 + 1) * 4];
            float4 p2 = *(const float4*)&xa[(c4 + 2) * 4];
            float4 q2 = *(const float4*)&xv[(c4 + 2) * 4];
            float4 p3 = *(const float4*)&xa[(c4 + 3) * 4];
            float4 q3 = *(const float4*)&xv[(c4 + 3) * 4];
            a0 = fma((double)p0.x, (double)q0.x, a0); a0 = fma((double)p0.y, (double)q0.y, a0);
            a0 = fma((double)p0.z, (double)q0.z, a0); a0 = fma((double)p0.w, (double)q0.w, a0);
            a1 = fma((double)p1.x, (double)q1.x, a1); a1 = fma((double)p1.y, (double)q1.y, a1);
            a1 = fma((double)p1.z, (double)q1.z, a1); a1 = fma((double)p1.w, (double)q1.w, a1);
            a2 = fma((double)p2.x, (double)q2.x, a2); a2 = fma((double)p2.y, (double)q2.y, a2);
            a2 = fma((double)p2.z, (double)q2.z, a2); a2 = fma((double)p2.w, (double)q2.w, a2);
            a3 = fma((double)p3.x, (double)q3.x, a3); a3 = fma((double)p3.y, (double)q3.y, a3);
            a3 = fma((double)p3.z, (double)q3.z, a3); a3 = fma((double)p3.w, (double)q3.w, a3);
        }
        double d = (a0 + a1) + (a2 + a3);
        d += __shfl_xor(d, 32);
        if (part == 0) {
            sc[wave][cidx] = 2.0 * d - xxd[(((size_t)b) << 12) + m];
            si[wave][cidx] = m;
        }
    }
    __syncthreads();

    // parallel exact ranking: lane i counts candidates strictly ahead of it
    if (lane < NCT) {
        double myv = sc[wave][lane];
        int    mym = si[wave][lane];
        int rank = 0;
        #pragma unroll
        for (int c = 0; c < NCT; ++c) {
            double v = sc[wave][c];
            int    m = si[wave][c];
            rank += (v > myv || (v == myv && m < mym)) ? 1 : 0;
        }
        if (rank < KNN) sel[wave][rank] = mym;
    }
    __syncthreads();

    float mx = -3.0e38f;
    #pragma unroll
    for (int j = 0; j < KNN; ++j)
        mx = fmaxf(mx, xb[(size_t)sel[wave][j] * CIN + lane]);
    feat[row * CIN + lane] = mx;
}

// ---------------- Kernel 4: conv (fp32 VALU) -> y + BN stats ----------------
// Channel-contiguous remap (R15-verified) + Wt pitch 132 (R18-verified, -4.5us):
// thread owns channels ch4..ch4+3 -> W read = 1 ds_read_b128, Fs = float4 per 4 c-iters,
// y store = 1 coalesced float4; pitch-132 staging avoids the pitch-128 32-way bank conflict.
// Accumulation order unchanged -> identical numerics.
__global__ __launch_bounds__(256) void conv_stats_kernel(const float* __restrict__ feat,
                                                         const float* __restrict__ W,
                                                         float* __restrict__ y,
                                                         float* __restrict__ st) {
    __shared__ float Wt[64 * 132];   // Wt[c][o], pitch 132
    __shared__ float Fs[64 * 64];
    __shared__ float bs[128], bs2[128];
    const int tid = threadIdx.x;
    const int n0  = blockIdx.x * 64;

    #pragma unroll
    for (int k = 0; k < 8; ++k) {
        int i4 = k * 256 + tid;          // float4 chunk 0..2047 of W (8192 floats)
        float4 w4 = ((const float4*)W)[i4];
        int o = i4 >> 4;                 // output channel (row of W)
        int c = (i4 & 15) * 4;           // input-channel group
        Wt[(c + 0) * 132 + o] = w4.x;
        Wt[(c + 1) * 132 + o] = w4.y;
        Wt[(c + 2) * 132 + o] = w4.z;
        Wt[(c + 3) * 132 + o] = w4.w;
    }
    for (int i = tid; i < 1024; i += 256)
        ((float4*)Fs)[i] = ((const float4*)(feat + (size_t)n0 * CIN))[i];
    if (tid < 128) { bs[tid] = 0.f; bs2[tid] = 0.f; }
    __syncthreads();

    const int ch4 = (tid & 31) * 4, rg = tid >> 5;
    float ts[4] = {0.f, 0.f, 0.f, 0.f}, ts2[4] = {0.f, 0.f, 0.f, 0.f};
    #pragma unroll
    for (int p = 0; p < 4; ++p) {
        const int r0 = p * 16 + rg * 2;
        float acc0[4] = {0.f, 0.f, 0.f, 0.f}, acc1[4] = {0.f, 0.f, 0.f, 0.f};
        for (int c4 = 0; c4 < 16; ++c4) {
            float4 f0v = *(const float4*)&Fs[r0 * 64 + c4 * 4];
            float4 f1v = *(const float4*)&Fs[(r0 + 1) * 64 + c4 * 4];
            const float f0a[4] = {f0v.x, f0v.y, f0v.z, f0v.w};
            const float f1a[4] = {f1v.x, f1v.y, f1v.z, f1v.w};
            #pragma unroll
            for (int cc = 0; cc < 4; ++cc) {
                float4 w = *(const float4*)&Wt[(c4 * 4 + cc) * 132 + ch4];
                const float wa[4] = {w.x, w.y, w.z, w.w};
                #pragma unroll
                for (int j = 0; j < 4; ++j) {
                    acc0[j] += f0a[cc] * wa[j];
                    acc1[j] += f1a[cc] * wa[j];
                }
            }
        }
        *(float4*)&y[(size_t)(n0 + r0)     * COUT + ch4] = make_float4(acc0[0], acc0[1], acc0[2], acc0[3]);
        *(float4*)&y[(size_t)(n0 + r0 + 1) * COUT + ch4] = make_float4(acc1[0], acc1[1], acc1[2], acc1[3]);
        #pragma unroll
        for (int j = 0; j < 4; ++j) {
            ts[j]  += acc0[j] + acc1[j];
            ts2[j] += acc0[j] * acc0[j] + acc1[j] * acc1[j];
        }
    }
    #pragma unroll
    for (int j = 0; j < 4; ++j) {
        atomicAdd(&bs [ch4 + j], ts[j]);
        atomicAdd(&bs2[ch4 + j], ts2[j]);
    }
    __syncthreads();
    if (tid < 128) {
        atomicAdd(&st[tid],       bs[tid]);
        atomicAdd(&st[128 + tid], bs2[tid]);
    }
}

// ---------------- Kernel 5: elementwise BN + LeakyReLU -> fp32 out ----------------
__global__ __launch_bounds__(256) void norm_out_kernel(const float* __restrict__ y,
                                                       const float* __restrict__ st,
                                                       const float* __restrict__ gamma,
                                                       const float* __restrict__ beta,
                                                       float* __restrict__ out) {
    size_t i = ((size_t)blockIdx.x * 256 + threadIdx.x) * 4;
    int c0 = (int)(i & 127);
    float4 v = *(const float4*)&y[i];
    float o[4];
    const float inv = 1.0f / (float)TOTROWS;
    #pragma unroll
    for (int j = 0; j < 4; ++j) {
        int c = c0 + j;
        float m  = st[c] * inv;
        float vr = st[128 + c] * inv - m * m;
        float sc = rsqrtf(vr + 1e-5f) * gamma[c];
        float t  = (((const float*)&v)[j] - m) * sc + beta[c];
        o[j] = (t >= 0.f) ? t : 0.01f * t;
    }
    *(float4*)&out[i] = make_float4(o[0], o[1], o[2], o[3]);
}

extern "C" void kernel_launch(void* const* d_in, const int* in_sizes, int n_in,
                              void* d_out, int out_size, void* d_ws, size_t ws_size,
                              hipStream_t stream) {
    (void)in_sizes; (void)n_in; (void)out_size; (void)ws_size;
    const float* x     = (const float*)d_in[0];
    const float* W     = (const float*)d_in[1];
    const float* gamma = (const float*)d_in[2];
    const float* beta  = (const float*)d_in[3];
    // d_in[4] is k == 8 (compile-time KNN)
    float* out = (float*)d_out;

    // workspace (~28.4 MB): xxn 128K | xxd 256K | cand 4M | feat 8M | region 16M (xpack 4M, reused as y) | st
    char*   ws    = (char*)d_ws;
    float*  xxn   = (float*)ws;
    double* xxd   = (double*)(ws + 131072);
    int*    cand  = (int*)(ws + 131072 + 262144);
    float*  feat  = (float*)(ws + 131072 + 262144 + 4194304);
    unsigned short* xpack = (unsigned short*)(ws + 131072 + 262144 + 4194304 + 8388608);
    float*  y     = (float*)xpack;   // xpack (4 MB used) dead after knn_cand; y is 16 MB fp32
    float*  st    = (float*)(ws + 131072 + 262144 + 4194304 + 8388608 + 16777216);

    hipMemsetAsync(st, 0, 256 * sizeof(float), stream);
    prep_kernel      <<<TOTROWS * 8 / 256, 256, 0, stream>>>(x, xpack, xxn, xxd);
    knn_cand_kernel  <<<dim3(NPTS / 64, 2, BATCH), 256, 0, stream>>>(xpack, xxn, cand);
    rerank_kernel    <<<TOTROWS / 4, 256, 0, stream>>>(x, xxd, cand, feat);
    conv_stats_kernel<<<TOTROWS / 64, 256, 0, stream>>>(feat, W, y, st);
    norm_out_kernel  <<<(TOTROWS * COUT) / (256 * 4), 256, 0, stream>>>(y, st, gamma, beta, out);
}